// Round 1
// baseline (538.479 us; speedup 1.0000x reference)
//
#include <hip/hip_runtime.h>

// N=8192, DIN=DH=DOUT=64, SPARSITY=0.01 -> ~82 nnz/row
// (row nnz ~ Binom(8192,0.01): mean 82, std 9; CAP=256 = 19 sigma)
#define NN 8192
#define DD 64
#define CAP 256   // per-row slab

// Pure streaming scan: one 256-thread block per FULL row (grid 8192).
// 8 unconditional float4 A-loads/thread (128 B in flight/thread), index-only
// LDS compaction, then a deferred per-entry lw gather in the epilogue and one
// coalesced slab write. No lw traffic inside the streaming loop, no global
// atomics.
__global__ __launch_bounds__(256) void scan_kernel(
    const float* __restrict__ A, const float* __restrict__ lw,
    int2* __restrict__ pairs, int* __restrict__ cnt)
{
    __shared__ int scnt;
    __shared__ int scols[CAP];

    const int tid = threadIdx.x;
    const int r   = blockIdx.x;

    if (tid == 0) scnt = 0;
    __syncthreads();

    const float4* A4 = (const float4*)(A + (size_t)r * NN);

    float4 a[8];
    #pragma unroll
    for (int k = 0; k < 8; ++k) a[k] = A4[tid + 256 * k];

    #pragma unroll
    for (int k = 0; k < 8; ++k) {
        const bool nzk = (a[k].x != 0.f) || (a[k].y != 0.f) ||
                         (a[k].z != 0.f) || (a[k].w != 0.f);
        if (nzk) {                       // ~27% of threads; exec-masked
            const int cbase = 4 * (tid + 256 * k);
            #define EMIT(comp, off)                                         \
                if (a[k].comp != 0.f) {                                     \
                    int p = atomicAdd(&scnt, 1);                            \
                    if (p < CAP) scols[p] = cbase + off;                    \
                }
            EMIT(x, 0) EMIT(y, 1) EMIT(z, 2) EMIT(w, 3)
            #undef EMIT
        }
    }
    __syncthreads();

    int n = scnt; if (n > CAP) n = CAP;
    if (tid == 0) cnt[r] = n;
    if (tid < n) {                       // deferred lw gather: ~82 scalar loads/row
        const int c = scols[tid];
        pairs[(size_t)r * CAP + tid] =
            make_int2(c, __float_as_int(lw[(size_t)r * NN + c]));
    }
}

// Layer pass (x3): 4 rows per 256-thread block, wave = row.
// Slab staged into LDS, zero-padded to x16, 16-way j-parallel batched float4
// gathers (4 in flight), shuffle-reduce, 64x64 linear from padded W^T.
__global__ __launch_bounds__(256) void layer_kernel(
    const float* __restrict__ xin,
    const int2* __restrict__ pairs, const int* __restrict__ cnt,
    const float* __restrict__ W, const float* __restrict__ bias,
    float* __restrict__ xout)
{
    __shared__ float  WT[DD * 65];
    __shared__ int2   spairs[4][CAP];
    __shared__ float4 sagg[4][16];

    const int tid  = threadIdx.x;
    const int wave = tid >> 6;
    const int lane = tid & 63;
    const int grp  = lane >> 4;
    const int l16  = lane & 15;

    for (int i = tid; i < DD * DD; i += 256)
        WT[(i & 63) * 65 + (i >> 6)] = W[i];   // stride-65: conflict-free

    const int r  = blockIdx.x * 4 + wave;
    const int n  = cnt[r];
    const int nr = (n + 15) & ~15;
    const size_t base = (size_t)r * CAP;

    for (int j = lane; j < n; j += 64)      spairs[wave][j] = pairs[base + j];
    for (int j = n + lane; j < nr; j += 64) spairs[wave][j] = make_int2(0, 0);
    __syncthreads();

    const float4* x4 = (const float4*)xin;
    float4 agg = make_float4(0.f, 0.f, 0.f, 0.f);
    for (int j0 = grp * 4; j0 < nr; j0 += 16) {
        int2 cv[4];
        #pragma unroll
        for (int t = 0; t < 4; ++t) cv[t] = spairs[wave][j0 + t];
        float4 xv[4];
        #pragma unroll
        for (int t = 0; t < 4; ++t)
            xv[t] = x4[(size_t)cv[t].x * (DD / 4) + l16];  // 4 gathers in flight
        #pragma unroll
        for (int t = 0; t < 4; ++t) {
            const float v = __int_as_float(cv[t].y);
            agg.x += v * xv[t].x; agg.y += v * xv[t].y;
            agg.z += v * xv[t].z; agg.w += v * xv[t].w;
        }
    }
    agg.x += __shfl_xor(agg.x, 16); agg.y += __shfl_xor(agg.y, 16);
    agg.z += __shfl_xor(agg.z, 16); agg.w += __shfl_xor(agg.w, 16);
    agg.x += __shfl_xor(agg.x, 32); agg.y += __shfl_xor(agg.y, 32);
    agg.z += __shfl_xor(agg.z, 32); agg.w += __shfl_xor(agg.w, 32);
    if (grp == 0) sagg[wave][l16] = agg;
    __syncthreads();

    const float* sa = (const float*)&sagg[wave][0];
    float acc = bias[lane];
    #pragma unroll 16
    for (int k = 0; k < DD; ++k)
        acc += sa[k] * WT[k * 65 + lane];
    xout[(size_t)r * DD + lane] = acc;
}

extern "C" void kernel_launch(void* const* d_in, const int* in_sizes, int n_in,
                              void* d_out, int out_size, void* d_ws, size_t ws_size,
                              hipStream_t stream) {
    const float* x  = (const float*)d_in[0];
    const float* A  = (const float*)d_in[1];
    const float* lw = (const float*)d_in[2];
    const float* W0 = (const float*)d_in[3];
    const float* b0 = (const float*)d_in[4];
    const float* W1 = (const float*)d_in[5];
    const float* b1 = (const float*)d_in[6];
    const float* W2 = (const float*)d_in[7];
    const float* b2 = (const float*)d_in[8];
    float* out = (float*)d_out;

    char* ws = (char*)d_ws;
    int2*  pairs = (int2*)ws;  ws += (size_t)NN * CAP * sizeof(int2);  // 16 MB
    int*   cnt   = (int*)ws;   ws += (size_t)NN * sizeof(int);
    float* bufA  = (float*)ws; ws += (size_t)NN * DD * sizeof(float);
    float* bufB  = (float*)ws;

    scan_kernel<<<NN, 256, 0, stream>>>(A, lw, pairs, cnt);
    layer_kernel<<<NN / 4, 256, 0, stream>>>(x,    pairs, cnt, W0, b0, bufA);
    layer_kernel<<<NN / 4, 256, 0, stream>>>(bufA, pairs, cnt, W1, b1, bufB);
    layer_kernel<<<NN / 4, 256, 0, stream>>>(bufB, pairs, cnt, W2, b2, out);
}

// Round 4
// 524.776 us; speedup vs baseline: 1.0261x; 1.0261x over previous
//
#include <hip/hip_runtime.h>

// N=8192, DIN=DH=DOUT=64, SPARSITY=0.01 -> ~82 nnz/row
// (row nnz ~ Binom(8192,0.01): mean 82, std 9; CAP=256 = 19 sigma)
#define NN  8192
#define DD  64
#define CAP 256

// Fused scan + layer-1: one 256-thread block per row (grid 8192).
// Phase A: pure A streaming (8 unconditional float4 loads/thread), index
//          compaction to LDS, deferred lw gather, slab write (for layers 2/3).
// Phase B: layer-1 aggregation straight from the LDS slab (16 groups x 16
//          lanes, full 256-thread parallelism), LDS tree reduce, 64x64 linear
//          read directly from L1/L2-resident W0.
__global__ __launch_bounds__(256) void scan_l1_kernel(
    const float* __restrict__ A, const float* __restrict__ lw,
    const float* __restrict__ x,
    const float* __restrict__ W0, const float* __restrict__ b0,
    int2* __restrict__ pairs, int* __restrict__ cnt,
    float* __restrict__ bufA)
{
    __shared__ int    scnt;
    __shared__ int    scols[CAP];
    __shared__ float  svals[CAP];
    __shared__ float4 sagg2[16][16];   // [group][dim-chunk]

    const int tid = threadIdx.x;
    const int r   = blockIdx.x;

    if (tid == 0) scnt = 0;
    __syncthreads();

    // ---- Phase A: stream A row, compact nonzero columns ----
    const float4* A4 = (const float4*)(A + (size_t)r * NN);
    float4 a[8];
    #pragma unroll
    for (int k = 0; k < 8; ++k) a[k] = A4[tid + 256 * k];

    #pragma unroll
    for (int k = 0; k < 8; ++k) {
        const bool nzk = (a[k].x != 0.f) || (a[k].y != 0.f) ||
                         (a[k].z != 0.f) || (a[k].w != 0.f);
        if (nzk) {                       // ~27% of threads; exec-masked
            const int cbase = 4 * (tid + 256 * k);
            #define EMIT(comp, off)                                         \
                if (a[k].comp != 0.f) {                                     \
                    int p = atomicAdd(&scnt, 1);                            \
                    if (p < CAP) scols[p] = cbase + off;                    \
                }
            EMIT(x, 0) EMIT(y, 1) EMIT(z, 2) EMIT(w, 3)
            #undef EMIT
        }
    }
    __syncthreads();

    int n = scnt; if (n > CAP) n = CAP;
    int nr = (n + 15) & ~15; if (nr == 0) nr = 16;
    if (tid == 0) cnt[r] = n;
    if (tid < n) {                       // deferred lw gather + slab write
        const int c = scols[tid];
        const float v = lw[(size_t)r * NN + c];
        svals[tid] = v;
        pairs[(size_t)r * CAP + tid] = make_int2(c, __float_as_int(v));
    } else if (tid < nr) {               // zero-pad to x16
        scols[tid] = 0;
        svals[tid] = 0.f;
    }
    __syncthreads();

    // ---- Phase B: layer-1 aggregation from LDS slab ----
    const int g   = tid >> 4;            // 16 groups
    const int l16 = tid & 15;            // 16 dim-chunks
    const float4* x4 = (const float4*)x;

    float4 agg = make_float4(0.f, 0.f, 0.f, 0.f);
    for (int j = g; j < nr; j += 16) {   // 16 slab entries in flight per iter
        const int   c = scols[j];
        const float v = svals[j];
        const float4 xv = x4[(size_t)c * (DD / 4) + l16];
        agg.x += v * xv.x; agg.y += v * xv.y;
        agg.z += v * xv.z; agg.w += v * xv.w;
    }
    sagg2[g][l16] = agg;
    __syncthreads();

    // tree reduce across the 16 groups
    #pragma unroll
    for (int s = 8; s >= 1; s >>= 1) {
        if (g < s) {
            float4 o = sagg2[g + s][l16];
            float4 m = sagg2[g][l16];
            m.x += o.x; m.y += o.y; m.z += o.z; m.w += o.w;
            sagg2[g][l16] = m;
        }
        __syncthreads();
    }

    // 64x64 linear: lane d reads its own W0 row (L1/L2-resident), agg via
    // LDS broadcast (same-address reads are conflict-free)
    if (tid < DD) {
        const float* sa = (const float*)&sagg2[0][0];  // final 64-float agg
        float acc = b0[tid];
        const float4* w4 = (const float4*)(W0 + (size_t)tid * DD);
        #pragma unroll
        for (int k4 = 0; k4 < 16; ++k4) {
            const float4 wv = w4[k4];
            acc += sa[4 * k4 + 0] * wv.x + sa[4 * k4 + 1] * wv.y
                 + sa[4 * k4 + 2] * wv.z + sa[4 * k4 + 3] * wv.w;
        }
        bufA[(size_t)r * DD + tid] = acc;
    }
}

// Layer pass (x2): 4 rows per 256-thread block, wave = row. Verified in R1.
__global__ __launch_bounds__(256) void layer_kernel(
    const float* __restrict__ xin,
    const int2* __restrict__ pairs, const int* __restrict__ cnt,
    const float* __restrict__ W, const float* __restrict__ bias,
    float* __restrict__ xout)
{
    __shared__ float  WT[DD * 65];
    __shared__ int2   spairs[4][CAP];
    __shared__ float4 sagg[4][16];

    const int tid  = threadIdx.x;
    const int wave = tid >> 6;
    const int lane = tid & 63;
    const int grp  = lane >> 4;
    const int l16  = lane & 15;

    for (int i = tid; i < DD * DD; i += 256)
        WT[(i & 63) * 65 + (i >> 6)] = W[i];   // stride-65: conflict-free

    const int r  = blockIdx.x * 4 + wave;
    const int n  = cnt[r];
    const int nr = (n + 15) & ~15;
    const size_t base = (size_t)r * CAP;

    for (int j = lane; j < n; j += 64)      spairs[wave][j] = pairs[base + j];
    for (int j = n + lane; j < nr; j += 64) spairs[wave][j] = make_int2(0, 0);
    __syncthreads();

    const float4* x4 = (const float4*)xin;
    float4 agg = make_float4(0.f, 0.f, 0.f, 0.f);
    for (int j0 = grp * 4; j0 < nr; j0 += 16) {
        int2 cv[4];
        #pragma unroll
        for (int t = 0; t < 4; ++t) cv[t] = spairs[wave][j0 + t];
        float4 xv[4];
        #pragma unroll
        for (int t = 0; t < 4; ++t)
            xv[t] = x4[(size_t)cv[t].x * (DD / 4) + l16];  // 4 gathers in flight
        #pragma unroll
        for (int t = 0; t < 4; ++t) {
            const float v = __int_as_float(cv[t].y);
            agg.x += v * xv[t].x; agg.y += v * xv[t].y;
            agg.z += v * xv[t].z; agg.w += v * xv[t].w;
        }
    }
    agg.x += __shfl_xor(agg.x, 16); agg.y += __shfl_xor(agg.y, 16);
    agg.z += __shfl_xor(agg.z, 16); agg.w += __shfl_xor(agg.w, 16);
    agg.x += __shfl_xor(agg.x, 32); agg.y += __shfl_xor(agg.y, 32);
    agg.z += __shfl_xor(agg.z, 32); agg.w += __shfl_xor(agg.w, 32);
    if (grp == 0) sagg[wave][l16] = agg;
    __syncthreads();

    const float* sa = (const float*)&sagg[wave][0];
    float acc = bias[lane];
    #pragma unroll 16
    for (int k = 0; k < DD; ++k)
        acc += sa[k] * WT[k * 65 + lane];
    xout[(size_t)r * DD + lane] = acc;
}

extern "C" void kernel_launch(void* const* d_in, const int* in_sizes, int n_in,
                              void* d_out, int out_size, void* d_ws, size_t ws_size,
                              hipStream_t stream) {
    const float* x  = (const float*)d_in[0];
    const float* A  = (const float*)d_in[1];
    const float* lw = (const float*)d_in[2];
    const float* W0 = (const float*)d_in[3];
    const float* b0 = (const float*)d_in[4];
    const float* W1 = (const float*)d_in[5];
    const float* b1 = (const float*)d_in[6];
    const float* W2 = (const float*)d_in[7];
    const float* b2 = (const float*)d_in[8];
    float* out = (float*)d_out;

    char* ws = (char*)d_ws;
    int2*  pairs = (int2*)ws;  ws += (size_t)NN * CAP * sizeof(int2);  // 16 MB
    int*   cnt   = (int*)ws;   ws += (size_t)NN * sizeof(int);
    float* bufA  = (float*)ws; ws += (size_t)NN * DD * sizeof(float);
    float* bufB  = (float*)ws;

    scan_l1_kernel<<<NN, 256, 0, stream>>>(A, lw, x, W0, b0, pairs, cnt, bufA);
    layer_kernel<<<NN / 4, 256, 0, stream>>>(bufA, pairs, cnt, W1, b1, bufB);
    layer_kernel<<<NN / 4, 256, 0, stream>>>(bufB, pairs, cnt, W2, b2, out);
}